// Round 1
// baseline (36279.010 us; speedup 1.0000x reference)
//
#include <hip/hip_runtime.h>
#include <hip/hip_bf16.h>

#define D_DIM 1024
#define T_STEPS 1024
#define BATCH 16
#define EPSF 1e-8f
#define MAXR 0.999f

typedef unsigned int u32;
typedef unsigned short u16;
typedef __attribute__((ext_vector_type(8))) short short8;
typedef __attribute__((ext_vector_type(4))) float floatx4;

__device__ __forceinline__ float bf_lo(u32 u) { return __uint_as_float(u << 16); }
__device__ __forceinline__ float bf_hi(u32 u) { return __uint_as_float(u & 0xffff0000u); }

__device__ __forceinline__ u16 f2bf(float f) {
  __hip_bfloat16 h = __float2bfloat16(f);
  return *reinterpret_cast<u16*>(&h);
}

// 256-thread block reduction; every thread returns the full sum.
__device__ __forceinline__ float block_reduce_256(float v, float* sred) {
  #pragma unroll
  for (int off = 32; off > 0; off >>= 1) v += __shfl_down(v, off, 64);
  const int w = threadIdx.x >> 6;
  __syncthreads();  // protect sred against back-to-back calls
  if ((threadIdx.x & 63) == 0) sred[w] = v;
  __syncthreads();
  return sred[0] + sred[1] + sred[2] + sred[3];
}

// out[j] = sum_i W[i][j] * (vin[i] / (||vin|| + eps))
__global__ __launch_bounds__(256) void mv_t(const float* __restrict__ W,
                                            const float* __restrict__ vin,
                                            float* __restrict__ vout) {
  __shared__ float sred[4];
  const int tid = threadIdx.x, j = blockIdx.x;
  const float4 uv = ((const float4*)vin)[tid];
  float ss = uv.x*uv.x + uv.y*uv.y + uv.z*uv.z + uv.w*uv.w;
  ss = block_reduce_256(ss, sred);
  const float s = 1.f / (sqrtf(ss) + EPSF);
  float a = 0.f;
  #pragma unroll
  for (int q = 0; q < 4; ++q) {
    const int i = q*256 + tid;
    a += W[(size_t)i*D_DIM + j] * vin[i];
  }
  a = block_reduce_256(a, sred);
  if (tid == 0) vout[j] = a * s;
}

// out[i] = sum_j W[i][j] * (vin[j] / (||vin|| + eps))
__global__ __launch_bounds__(256) void mv_n(const float* __restrict__ W,
                                            const float* __restrict__ vin,
                                            float* __restrict__ vout) {
  __shared__ float sred[4];
  const int tid = threadIdx.x, i = blockIdx.x;
  const float4 vv = ((const float4*)vin)[tid];
  float ss = vv.x*vv.x + vv.y*vv.y + vv.z*vv.z + vv.w*vv.w;
  ss = block_reduce_256(ss, sred);
  const float s = 1.f / (sqrtf(ss) + EPSF);
  const float4 wv = ((const float4*)(W + (size_t)i*D_DIM))[tid];
  float a = wv.x*vv.x + wv.y*vv.y + wv.z*vv.z + wv.w*vv.w;
  a = block_reduce_256(a, sred);
  if (tid == 0) vout[i] = a * s;
}

// sigma = ||u3_raw||^2 / (||u3_raw|| + eps)   (== |u^T W v| exactly)
__global__ __launch_bounds__(256) void sigma_k(const float* __restrict__ v,
                                               float* __restrict__ sig) {
  __shared__ float sred[4];
  const int tid = threadIdx.x;
  const float4 x4 = ((const float4*)v)[tid];
  float ss = x4.x*x4.x + x4.y*x4.y + x4.z*x4.z + x4.w*x4.w;
  ss = block_reduce_256(ss, sred);
  if (tid == 0) {
    const float n = sqrtf(ss);
    *sig = ss / (n + EPSF);
  }
}

// Weff_bf16[d][k] = bf16( Wh[d][k] * sigmoid(lr[d]) * MAXR / (sigma + eps) )
__global__ __launch_bounds__(256) void make_weff(const float* __restrict__ Wh,
                                                 const float* __restrict__ lr,
                                                 const float* __restrict__ sig,
                                                 u16* __restrict__ Weff) {
  const int idx = blockIdx.x*256 + threadIdx.x;  // float4 index, 0..262143
  const int d = idx >> 8;
  const float sigma = *sig;
  const float r = MAXR / (1.f + expf(-lr[d]));
  const float scale = r / (sigma + EPSF);
  const float4 w = ((const float4*)Wh)[idx];
  ushort4 o;
  o.x = f2bf(w.x*scale); o.y = f2bf(w.y*scale);
  o.z = f2bf(w.z*scale); o.w = f2bf(w.w*scale);
  ((ushort4*)Weff)[idx] = o;
}

// A_pre[m][n] = sum_k X[m][k]*Wx[n][k] + bias[n], bf16 MFMA 16x16x32, 128x128 tiles
__global__ __launch_bounds__(256) void gemm_xwT(const float* __restrict__ X,
                                                const float* __restrict__ Wx,
                                                const float* __restrict__ bias,
                                                float* __restrict__ Apre) {
  __shared__ __align__(16) u16 As[128*32];
  __shared__ __align__(16) u16 Bs[128*32];
  const int tid = threadIdx.x;
  const int bm = blockIdx.x & 127;
  const int bn = blockIdx.x >> 7;
  const int m0 = bm << 7, n0 = bn << 7;
  const int lane = tid & 63, wave = tid >> 6;
  const int wm = (wave & 1) << 6, wn = (wave >> 1) << 6;
  const int fm = lane & 15, kq = lane >> 4;

  floatx4 acc[4][4];
  const floatx4 zero4 = {0.f, 0.f, 0.f, 0.f};
  #pragma unroll
  for (int i = 0; i < 4; ++i)
    #pragma unroll
    for (int j = 0; j < 4; ++j) acc[i][j] = zero4;

  for (int k0 = 0; k0 < 1024; k0 += 32) {
    #pragma unroll
    for (int i = 0; i < 4; ++i) {
      const int c = i*256 + tid;
      const int r = c >> 3, cc = (c & 7) << 2;
      const float4 av = *(const float4*)&X[(size_t)(m0 + r)*1024 + k0 + cc];
      const float4 bv = *(const float4*)&Wx[(size_t)(n0 + r)*1024 + k0 + cc];
      ushort4 ap, bp;
      ap.x = f2bf(av.x); ap.y = f2bf(av.y); ap.z = f2bf(av.z); ap.w = f2bf(av.w);
      bp.x = f2bf(bv.x); bp.y = f2bf(bv.y); bp.z = f2bf(bv.z); bp.w = f2bf(bv.w);
      *(ushort4*)&As[r*32 + cc] = ap;
      *(ushort4*)&Bs[r*32 + cc] = bp;
    }
    __syncthreads();
    short8 afr[4], bfr[4];
    #pragma unroll
    for (int mi = 0; mi < 4; ++mi)
      afr[mi] = *(const short8*)&As[(wm + mi*16 + fm)*32 + kq*8];
    #pragma unroll
    for (int ni = 0; ni < 4; ++ni)
      bfr[ni] = *(const short8*)&Bs[(wn + ni*16 + fm)*32 + kq*8];
    #pragma unroll
    for (int mi = 0; mi < 4; ++mi)
      #pragma unroll
      for (int ni = 0; ni < 4; ++ni)
        acc[mi][ni] = __builtin_amdgcn_mfma_f32_16x16x32_bf16(afr[mi], bfr[ni], acc[mi][ni], 0, 0, 0);
    __syncthreads();
  }
  const int cn = lane & 15, rb = (lane >> 4) << 2;
  #pragma unroll
  for (int mi = 0; mi < 4; ++mi) {
    #pragma unroll
    for (int ni = 0; ni < 4; ++ni) {
      const int n = n0 + wn + ni*16 + cn;
      const float bv = bias[n];
      #pragma unroll
      for (int r = 0; r < 4; ++r) {
        const int m = m0 + wm + mi*16 + rb + r;
        Apre[(size_t)m*1024 + n] = acc[mi][ni][r] + bv;
      }
    }
  }
}

// Persistent scan: 512 wgs = 16 batch-groups x 32 dim-slices (32 dims each).
// W_eff slice lives in LDS (bf16, row-rotated swizzle). h exchanged through
// h_all region of d_out (each address written exactly once). Per-group
// monotonic-counter barrier with explicit agent fences; patience-bounded.
__global__ __launch_bounds__(256, 2) void scan_rnn(const float* __restrict__ Z,
                                                   const float* __restrict__ H0,
                                                   const u16* __restrict__ Weff,
                                                   float* __restrict__ outs,
                                                   float* __restrict__ hall,
                                                   u32* cnt) {
  __shared__ __align__(16) u16 Wl[32*1024];  // 64 KiB exactly
  const int tid = threadIdx.x;
  const int wg = blockIdx.x;
  const int b = wg & 15;        // batch row (group id); same XCD under round-robin
  const int s = wg >> 4;        // dim-slice 0..31
  const int d0 = s << 5;

  // Load W slice rows d0..d0+31, rotate row r's 16B-chunks by r (bank de-alias).
  {
    const uint4* Wg = (const uint4*)(Weff + (size_t)d0 * 1024);
    uint4* Wls = (uint4*)Wl;
    for (int c = tid; c < 32*128; c += 256) {
      const int r = c >> 7, cc = c & 127;
      Wls[(r << 7) + ((cc + r) & 127)] = Wg[c];
    }
  }
  // h_all[0][b][d0..d0+32) = h0 slice
  if (tid < 32) hall[(size_t)b*D_DIM + d0 + tid] = H0[b*D_DIM + d0 + tid];
  __syncthreads();  // drains global stores (vmcnt 0) + LDS ready

  int pat = 1 << 20;  // global spin budget: deadlock -> clean wrong answer, no hang
  if (tid == 0) {
    __builtin_amdgcn_fence(__ATOMIC_RELEASE, "agent");
    __hip_atomic_fetch_add(&cnt[b], 1u, __ATOMIC_RELAXED, __HIP_MEMORY_SCOPE_AGENT);
    while (__hip_atomic_load(&cnt[b], __ATOMIC_RELAXED, __HIP_MEMORY_SCOPE_AGENT) < 32u) {
      if (--pat <= 0) break;
      __builtin_amdgcn_s_sleep(1);
    }
    __builtin_amdgcn_fence(__ATOMIC_ACQUIRE, "agent");
  }
  __syncthreads();

  const int lane = tid & 63;
  const int wv = tid >> 6;
  const int dl = (wv << 3) + (lane >> 3);  // 0..31: dim within slice
  const int kc = lane & 7;                 // 0..7: 128-wide k chunk
  const u16* wbase = Wl + (dl << 10);
  const int cb = (kc << 4) + dl;           // swizzled chunk base

  for (int t = 0; t < T_STEPS; ++t) {
    const float* hp = hall + (size_t)t*BATCH*D_DIM + b*D_DIM + (kc << 7);
    float acc = 0.f;
    #pragma unroll
    for (int j = 0; j < 16; ++j) {
      const uint4 w4 = *(const uint4*)(wbase + (((cb + j) & 127) << 3));
      const float4 ha = *(const float4*)(hp + j*8);
      const float4 hb = *(const float4*)(hp + j*8 + 4);
      acc += bf_lo(w4.x)*ha.x + bf_hi(w4.x)*ha.y;
      acc += bf_lo(w4.y)*ha.z + bf_hi(w4.y)*ha.w;
      acc += bf_lo(w4.z)*hb.x + bf_hi(w4.z)*hb.y;
      acc += bf_lo(w4.w)*hb.z + bf_hi(w4.w)*hb.w;
    }
    // reduce across the 8 kc lanes (lane bits 0..2)
    acc += __shfl_xor(acc, 1, 64);
    acc += __shfl_xor(acc, 2, 64);
    acc += __shfl_xor(acc, 4, 64);
    if (kc == 0) {
      const size_t base = (size_t)t*BATCH*D_DIM + b*D_DIM + d0 + dl;
      const float a = outs[base];           // A_pre (x@Wx^T + bias), in place
      const float hn = tanhf(acc + a);
      const float zv = Z[base];
      const float gate = zv / (1.f + expf(-zv));  // z * sigmoid(z)
      outs[base] = hn * gate;
      hall[base + BATCH*D_DIM] = hn;        // h_all[t+1]
    }
    __syncthreads();  // drains the global stores of all waves to L2
    if (tid == 0) {
      __builtin_amdgcn_fence(__ATOMIC_RELEASE, "agent");  // L2 writeback -> device visible
      __hip_atomic_fetch_add(&cnt[b], 1u, __ATOMIC_RELAXED, __HIP_MEMORY_SCOPE_AGENT);
      const u32 tgt = 32u * (u32)(t + 2);
      while (__hip_atomic_load(&cnt[b], __ATOMIC_RELAXED, __HIP_MEMORY_SCOPE_AGENT) < tgt) {
        if (--pat <= 0) break;
        __builtin_amdgcn_s_sleep(1);
      }
      __builtin_amdgcn_fence(__ATOMIC_ACQUIRE, "agent");  // invalidate stale h lines
    }
    __syncthreads();
  }
}

extern "C" void kernel_launch(void* const* d_in, const int* in_sizes, int n_in,
                              void* d_out, int out_size, void* d_ws, size_t ws_size,
                              hipStream_t stream) {
  const float* x  = (const float*)d_in[0];
  const float* z  = (const float*)d_in[1];
  const float* h0 = (const float*)d_in[2];
  const float* Wx = (const float*)d_in[3];
  const float* Wh = (const float*)d_in[4];
  const float* lr = (const float*)d_in[5];
  const float* bb = (const float*)d_in[6];
  const float* u0 = (const float*)d_in[7];

  float* outp = (float*)d_out;
  float* outs = outp;                                    // [1024][16][1024]
  float* hall = outp + (size_t)T_STEPS*BATCH*D_DIM;      // [1025][16][1024]

  char* ws = (char*)d_ws;
  u16* Weff = (u16*)ws;                         // 2 MiB bf16
  float* tA  = (float*)(ws + 2097152);
  float* tB  = (float*)(ws + 2101248);
  float* sg  = (float*)(ws + 2105344);
  u32* cnt   = (u32*)(ws + 2105600);            // 16 counters

  hipMemsetAsync(cnt, 0, 64, stream);

  // 3-step power iteration (normalization folded into each matvec)
  mv_t<<<1024, 256, 0, stream>>>(Wh, u0, tA);   // v1_raw
  mv_n<<<1024, 256, 0, stream>>>(Wh, tA, tB);   // u1_raw
  mv_t<<<1024, 256, 0, stream>>>(Wh, tB, tA);   // v2_raw
  mv_n<<<1024, 256, 0, stream>>>(Wh, tA, tB);   // u2_raw
  mv_t<<<1024, 256, 0, stream>>>(Wh, tB, tA);   // v3_raw
  mv_n<<<1024, 256, 0, stream>>>(Wh, tA, tB);   // u3_raw = W v3
  sigma_k<<<1, 256, 0, stream>>>(tB, sg);
  make_weff<<<1024, 256, 0, stream>>>(Wh, lr, sg, Weff);

  // A_pre = x @ Wx^T + b, written into the outs region (overwritten in-place by scan)
  gemm_xwT<<<1024, 256, 0, stream>>>(x, Wx, bb, outs);

  // Persistent sequential scan
  scan_rnn<<<512, 256, 0, stream>>>(z, h0, Weff, outs, hall, cnt);
}

// Round 2
// 5596.485 us; speedup vs baseline: 6.4825x; 6.4825x over previous
//
#include <hip/hip_runtime.h>
#include <hip/hip_bf16.h>

#define D_DIM 1024
#define T_STEPS 1024
#define BATCH 16
#define EPSF 1e-8f
#define MAXR 0.999f

typedef unsigned int u32;
typedef unsigned long long u64;
typedef unsigned short u16;
typedef __attribute__((ext_vector_type(8))) short short8;
typedef __attribute__((ext_vector_type(4))) float floatx4;

__device__ __forceinline__ float bf_lo(u32 u) { return __uint_as_float(u << 16); }
__device__ __forceinline__ float bf_hi(u32 u) { return __uint_as_float(u & 0xffff0000u); }

__device__ __forceinline__ u16 f2bf(float f) {
  __hip_bfloat16 h = __float2bfloat16(f);
  return *reinterpret_cast<u16*>(&h);
}

// 256-thread block reduction; every thread returns the full sum.
__device__ __forceinline__ float block_reduce_256(float v, float* sred) {
  #pragma unroll
  for (int off = 32; off > 0; off >>= 1) v += __shfl_down(v, off, 64);
  const int w = threadIdx.x >> 6;
  __syncthreads();
  if ((threadIdx.x & 63) == 0) sred[w] = v;
  __syncthreads();
  return sred[0] + sred[1] + sred[2] + sred[3];
}

// out[j] = sum_i W[i][j] * (vin[i] / (||vin|| + eps))
__global__ __launch_bounds__(256) void mv_t(const float* __restrict__ W,
                                            const float* __restrict__ vin,
                                            float* __restrict__ vout) {
  __shared__ float sred[4];
  const int tid = threadIdx.x, j = blockIdx.x;
  const float4 uv = ((const float4*)vin)[tid];
  float ss = uv.x*uv.x + uv.y*uv.y + uv.z*uv.z + uv.w*uv.w;
  ss = block_reduce_256(ss, sred);
  const float s = 1.f / (sqrtf(ss) + EPSF);
  float a = 0.f;
  #pragma unroll
  for (int q = 0; q < 4; ++q) {
    const int i = q*256 + tid;
    a += W[(size_t)i*D_DIM + j] * vin[i];
  }
  a = block_reduce_256(a, sred);
  if (tid == 0) vout[j] = a * s;
}

// out[i] = sum_j W[i][j] * (vin[j] / (||vin|| + eps))
__global__ __launch_bounds__(256) void mv_n(const float* __restrict__ W,
                                            const float* __restrict__ vin,
                                            float* __restrict__ vout) {
  __shared__ float sred[4];
  const int tid = threadIdx.x, i = blockIdx.x;
  const float4 vv = ((const float4*)vin)[tid];
  float ss = vv.x*vv.x + vv.y*vv.y + vv.z*vv.z + vv.w*vv.w;
  ss = block_reduce_256(ss, sred);
  const float s = 1.f / (sqrtf(ss) + EPSF);
  const float4 wv = ((const float4*)(W + (size_t)i*D_DIM))[tid];
  float a = wv.x*vv.x + wv.y*vv.y + wv.z*vv.z + wv.w*vv.w;
  a = block_reduce_256(a, sred);
  if (tid == 0) vout[i] = a * s;
}

// sigma = ||u3_raw||^2 / (||u3_raw|| + eps)   (== |u^T W v| exactly)
__global__ __launch_bounds__(256) void sigma_k(const float* __restrict__ v,
                                               float* __restrict__ sig) {
  __shared__ float sred[4];
  const int tid = threadIdx.x;
  const float4 x4 = ((const float4*)v)[tid];
  float ss = x4.x*x4.x + x4.y*x4.y + x4.z*x4.z + x4.w*x4.w;
  ss = block_reduce_256(ss, sred);
  if (tid == 0) {
    const float n = sqrtf(ss);
    *sig = ss / (n + EPSF);
  }
}

// Weff_bf16[d][k] = bf16( Wh[d][k] * sigmoid(lr[d]) * MAXR / (sigma + eps) )
__global__ __launch_bounds__(256) void make_weff(const float* __restrict__ Wh,
                                                 const float* __restrict__ lr,
                                                 const float* __restrict__ sig,
                                                 u16* __restrict__ Weff) {
  const int idx = blockIdx.x*256 + threadIdx.x;
  const int d = idx >> 8;
  const float sigma = *sig;
  const float r = MAXR / (1.f + expf(-lr[d]));
  const float scale = r / (sigma + EPSF);
  const float4 w = ((const float4*)Wh)[idx];
  ushort4 o;
  o.x = f2bf(w.x*scale); o.y = f2bf(w.y*scale);
  o.z = f2bf(w.z*scale); o.w = f2bf(w.w*scale);
  ((ushort4*)Weff)[idx] = o;
}

// A_pre[m][n] = sum_k X[m][k]*Wx[n][k] + bias[n], bf16 MFMA 16x16x32, 128x128 tiles
__global__ __launch_bounds__(256) void gemm_xwT(const float* __restrict__ X,
                                                const float* __restrict__ Wx,
                                                const float* __restrict__ bias,
                                                float* __restrict__ Apre) {
  __shared__ __align__(16) u16 As[128*32];
  __shared__ __align__(16) u16 Bs[128*32];
  const int tid = threadIdx.x;
  const int bm = blockIdx.x & 127;
  const int bn = blockIdx.x >> 7;
  const int m0 = bm << 7, n0 = bn << 7;
  const int lane = tid & 63, wave = tid >> 6;
  const int wm = (wave & 1) << 6, wn = (wave >> 1) << 6;
  const int fm = lane & 15, kq = lane >> 4;

  floatx4 acc[4][4];
  const floatx4 zero4 = {0.f, 0.f, 0.f, 0.f};
  #pragma unroll
  for (int i = 0; i < 4; ++i)
    #pragma unroll
    for (int j = 0; j < 4; ++j) acc[i][j] = zero4;

  for (int k0 = 0; k0 < 1024; k0 += 32) {
    #pragma unroll
    for (int i = 0; i < 4; ++i) {
      const int c = i*256 + tid;
      const int r = c >> 3, cc = (c & 7) << 2;
      const float4 av = *(const float4*)&X[(size_t)(m0 + r)*1024 + k0 + cc];
      const float4 bv = *(const float4*)&Wx[(size_t)(n0 + r)*1024 + k0 + cc];
      ushort4 ap, bp;
      ap.x = f2bf(av.x); ap.y = f2bf(av.y); ap.z = f2bf(av.z); ap.w = f2bf(av.w);
      bp.x = f2bf(bv.x); bp.y = f2bf(bv.y); bp.z = f2bf(bv.z); bp.w = f2bf(bv.w);
      *(ushort4*)&As[r*32 + cc] = ap;
      *(ushort4*)&Bs[r*32 + cc] = bp;
    }
    __syncthreads();
    short8 afr[4], bfr[4];
    #pragma unroll
    for (int mi = 0; mi < 4; ++mi)
      afr[mi] = *(const short8*)&As[(wm + mi*16 + fm)*32 + kq*8];
    #pragma unroll
    for (int ni = 0; ni < 4; ++ni)
      bfr[ni] = *(const short8*)&Bs[(wn + ni*16 + fm)*32 + kq*8];
    #pragma unroll
    for (int mi = 0; mi < 4; ++mi)
      #pragma unroll
      for (int ni = 0; ni < 4; ++ni)
        acc[mi][ni] = __builtin_amdgcn_mfma_f32_16x16x32_bf16(afr[mi], bfr[ni], acc[mi][ni], 0, 0, 0);
    __syncthreads();
  }
  const int cn = lane & 15, rb = (lane >> 4) << 2;
  #pragma unroll
  for (int mi = 0; mi < 4; ++mi) {
    #pragma unroll
    for (int ni = 0; ni < 4; ++ni) {
      const int n = n0 + wn + ni*16 + cn;
      const float bv = bias[n];
      #pragma unroll
      for (int r = 0; r < 4; ++r) {
        const int m = m0 + wm + mi*16 + rb + r;
        Apre[(size_t)m*1024 + n] = acc[mi][ni][r] + bv;
      }
    }
  }
}

// Persistent scan v2: 1024 wgs = 16 batch-groups x 64 dim-slices (16 dims each).
// NO cache-flushing fences. All cross-wg data (h rows, flags) moves through
// relaxed AGENT-scope atomics (sc1 -> coherence point), ordered by waitcnt /
// syncthreads-drain + per-wg padded flag words. W slice in LDS (bf16,
// XOR-swizzled); h[t] staged to LDS once per step.
__global__ __launch_bounds__(256, 4) void scan_rnn(const float* __restrict__ Z,
                                                   const float* __restrict__ H0,
                                                   const u16* __restrict__ Weff,
                                                   float* __restrict__ outs,
                                                   float* __restrict__ hall,
                                                   u32* __restrict__ flg) {
  __shared__ __align__(16) u16 Wl[16*1024];   // 32 KB, uint4 units XOR-swizzled per row
  __shared__ __align__(16) float Hl[1024];    // 4 KB, float4 units XOR-swizzled
  const int tid = threadIdx.x;
  const int b = blockIdx.x & 15;      // batch-row group
  const int s = blockIdx.x >> 4;      // dim-slice 0..63
  const int d0 = s << 4;

  // Stage W slice rows d0..d0+15 into LDS; swizzle 16B unit u -> u ^ ((u>>3)&7)
  {
    const uint4* Wg = (const uint4*)(Weff + (size_t)d0 * 1024);
    uint4* Wl4 = (uint4*)Wl;
    #pragma unroll
    for (int i = 0; i < 8; ++i) {
      const int c = i*256 + tid;        // 0..2047
      const int r = c >> 7, u = c & 127;
      Wl4[(r << 7) + (u ^ ((u >> 3) & 7))] = Wg[c];
    }
  }
  // Publish h_all[0] slice via agent-scope stores (bypass L2, land at LIC)
  if (tid < 16) {
    const float h0v = H0[b*D_DIM + d0 + tid];
    __hip_atomic_store((u32*)&hall[(size_t)b*D_DIM + d0 + tid], __float_as_uint(h0v),
                       __ATOMIC_RELAXED, __HIP_MEMORY_SCOPE_AGENT);
  }
  __syncthreads();  // drains vmcnt for all waves
  if (tid == 0) {
    __builtin_amdgcn_s_waitcnt(0);
    __hip_atomic_store(&flg[((b << 6) + s) << 5], 1u,
                       __ATOMIC_RELAXED, __HIP_MEMORY_SCOPE_AGENT);
  }

  const int lane = tid & 63, wv = tid >> 6;
  const int kc = lane & 15;         // k-chunk of 64 floats
  const int kcl = kc & 7;
  const int dlq = lane >> 4;        // 0..3
  const int dl = (wv << 2) + dlq;   // 0..15 dim within slice
  const uint4* Wrow = ((const uint4*)Wl) + (dl << 7);
  const float4* H4 = (const float4*)Hl;
  int pat = 1 << 21;                // poll budget: deadlock -> clean finish, no hang

  for (int t = 0; t < T_STEPS; ++t) {
    const size_t base = (size_t)t*BATCH*D_DIM + (size_t)b*D_DIM + d0 + dl;
    // Prefetch epilogue operands (addresses independent of h)
    float a_pre = 0.f, zv = 0.f;
    if (kc == 0) { a_pre = outs[base]; zv = Z[base]; }

    // Wave 0: poll this group's 64 flags (one padded word per slice)
    if (tid < 64) {
      const u32 tgt = (u32)(t + 1);
      while (pat > 0) {
        const u32 v = __hip_atomic_load(&flg[((b << 6) + lane) << 5],
                                        __ATOMIC_RELAXED, __HIP_MEMORY_SCOPE_AGENT);
        if (__all((int)(v >= tgt))) break;
        --pat;
        __builtin_amdgcn_s_sleep(2);
      }
    }
    __syncthreads();

    // Stage h[t] (4 KB) into LDS via agent-scope 64-bit loads
    {
      const u64* h64 = (const u64*)(hall + (size_t)t*BATCH*D_DIM + (size_t)b*D_DIM);
      const u64 p0 = __hip_atomic_load(h64 + tid*2,     __ATOMIC_RELAXED, __HIP_MEMORY_SCOPE_AGENT);
      const u64 p1 = __hip_atomic_load(h64 + tid*2 + 1, __ATOMIC_RELAXED, __HIP_MEMORY_SCOPE_AGENT);
      ulonglong2 pv; pv.x = p0; pv.y = p1;
      ((ulonglong2*)Hl)[tid ^ ((tid >> 4) & 7)] = pv;  // float4 unit v=tid, v>>4 = chunk
    }
    __syncthreads();

    // dot: dim d0+dl, k-chunk kc (64 elems)
    float acc = 0.f;
    #pragma unroll
    for (int j = 0; j < 8; ++j) {
      const uint4 w4 = Wrow[(kc << 3) + (j ^ kcl)];
      const float4 ha = H4[(kc << 4) + (((j << 1)    ) ^ kcl)];
      const float4 hb = H4[(kc << 4) + (((j << 1) + 1) ^ kcl)];
      acc += bf_lo(w4.x)*ha.x + bf_hi(w4.x)*ha.y;
      acc += bf_lo(w4.y)*ha.z + bf_hi(w4.y)*ha.w;
      acc += bf_lo(w4.z)*hb.x + bf_hi(w4.z)*hb.y;
      acc += bf_lo(w4.w)*hb.z + bf_hi(w4.w)*hb.w;
    }
    // reduce across 16 kc lanes (lane bits 0..3)
    acc += __shfl_xor(acc, 1, 64);
    acc += __shfl_xor(acc, 2, 64);
    acc += __shfl_xor(acc, 4, 64);
    acc += __shfl_xor(acc, 8, 64);

    if (kc == 0) {
      const float hn = tanhf(acc + a_pre);
      const float gate = zv / (1.f + expf(-zv));
      outs[base] = hn * gate;                       // plain store (read back only by host)
      __hip_atomic_store((u32*)&hall[base + BATCH*D_DIM], __float_as_uint(hn),
                         __ATOMIC_RELAXED, __HIP_MEMORY_SCOPE_AGENT);
    }
    __syncthreads();  // drains each wave's stores (vmcnt 0) before the flag
    if (tid == 0) {
      __builtin_amdgcn_s_waitcnt(0);
      __hip_atomic_store(&flg[((b << 6) + s) << 5], (u32)(t + 2),
                         __ATOMIC_RELAXED, __HIP_MEMORY_SCOPE_AGENT);
    }
  }
}

extern "C" void kernel_launch(void* const* d_in, const int* in_sizes, int n_in,
                              void* d_out, int out_size, void* d_ws, size_t ws_size,
                              hipStream_t stream) {
  const float* x  = (const float*)d_in[0];
  const float* z  = (const float*)d_in[1];
  const float* h0 = (const float*)d_in[2];
  const float* Wx = (const float*)d_in[3];
  const float* Wh = (const float*)d_in[4];
  const float* lr = (const float*)d_in[5];
  const float* bb = (const float*)d_in[6];
  const float* u0 = (const float*)d_in[7];

  float* outp = (float*)d_out;
  float* outs = outp;                                    // [1024][16][1024]
  float* hall = outp + (size_t)T_STEPS*BATCH*D_DIM;      // [1025][16][1024]

  char* ws = (char*)d_ws;
  u16* Weff = (u16*)ws;                         // 2 MiB bf16
  float* tA  = (float*)(ws + 2097152);
  float* tB  = (float*)(ws + 2101248);
  float* sg  = (float*)(ws + 2105344);
  u32* flg   = (u32*)(ws + 2105600);            // 16*64 flags, 128B apart = 128 KiB

  hipMemsetAsync(flg, 0, 16*64*128, stream);

  // 3-step power iteration (normalization folded into each matvec)
  mv_t<<<1024, 256, 0, stream>>>(Wh, u0, tA);   // v1_raw
  mv_n<<<1024, 256, 0, stream>>>(Wh, tA, tB);   // u1_raw
  mv_t<<<1024, 256, 0, stream>>>(Wh, tB, tA);   // v2_raw
  mv_n<<<1024, 256, 0, stream>>>(Wh, tA, tB);   // u2_raw
  mv_t<<<1024, 256, 0, stream>>>(Wh, tB, tA);   // v3_raw
  mv_n<<<1024, 256, 0, stream>>>(Wh, tA, tB);   // u3_raw = W v3
  sigma_k<<<1, 256, 0, stream>>>(tB, sg);
  make_weff<<<1024, 256, 0, stream>>>(Wh, lr, sg, Weff);

  // A_pre = x @ Wx^T + b, written into the outs region (overwritten in-place by scan)
  gemm_xwT<<<1024, 256, 0, stream>>>(x, Wx, bb, outs);

  // Persistent sequential scan (no fences; sc1 atomic exchange through LIC)
  scan_rnn<<<1024, 256, 0, stream>>>(z, h0, Weff, outs, hall, flg);
}